// Round 10
// baseline (376.387 us; speedup 1.0000x reference)
//
#include <hip/hip_runtime.h>
#include <hip/hip_bf16.h>

typedef __attribute__((ext_vector_type(8))) short short8;       // 8 bf16 (A/B frag)
typedef __attribute__((ext_vector_type(4))) float floatx4;      // C/D frag
typedef __attribute__((ext_vector_type(4))) unsigned short ushort4v;

__device__ inline unsigned short f2bf(float x) {                 // RNE f32->bf16 bits
    unsigned int u = __float_as_uint(x);
    u += 0x7FFFu + ((u >> 16) & 1u);
    return (unsigned short)(u >> 16);
}
__device__ inline float bf2f(unsigned short h) {
    return __uint_as_float(((unsigned int)h) << 16);
}
__device__ inline float blo(unsigned int u) { return __uint_as_float(u << 16); }
__device__ inline float bhi(unsigned int u) { return __uint_as_float(u & 0xFFFF0000u); }

#if defined(__has_builtin)
#if __has_builtin(__builtin_amdgcn_exp2f)
#define EXP2F(x) __builtin_amdgcn_exp2f(x)
#else
#define EXP2F(x) exp2f(x)
#endif
#if __has_builtin(__builtin_amdgcn_update_dpp)
#define HAVE_DPP 1
#endif
#else
#define EXP2F(x) exp2f(x)
#endif

// DPP butterfly add: x + shuffle(x) — pure VALU, no LDS pipe, no lgkmcnt wait.
#ifdef HAVE_DPP
template <int CTRL>
__device__ __forceinline__ float dppadd(float x) {
    int s = __builtin_amdgcn_update_dpp(0, __float_as_int(x), CTRL, 0xf, 0xf, true);
    return x + __int_as_float(s);
}
// sum over the 8 lanes of a g-octet (lane bits 0..2): xor1, xor2, xor7-mirror
__device__ __forceinline__ float red8(float x) {
    x = dppadd<0xB1>(x);    // quad_perm [1,0,3,2]  = xor 1
    x = dppadd<0x4E>(x);    // quad_perm [2,3,0,1]  = xor 2
    x = dppadd<0x141>(x);   // row_half_mirror      = xor 7 (valid: quads uniform)
    return x;
}
__device__ __forceinline__ float xor8add(float x) {
    return dppadd<0x128>(x);   // row_ror:8 = xor 8 within 16-lane row
}
#else
__device__ __forceinline__ float red8(float x) {
    x += __shfl_xor(x, 1); x += __shfl_xor(x, 2); x += __shfl_xor(x, 4);
    return x;
}
__device__ __forceinline__ float xor8add(float x) { return x + __shfl_xor(x, 8); }
#endif

template <bool B> struct BC { static constexpr bool value = B; };

// -------- fused: weight prep (blocks 0..831) + degree hist (blocks 832+) ---
__global__ __launch_bounds__(256) void wprep_hist(
    const float* __restrict__ wq1, const float* __restrict__ bq1,
    const float* __restrict__ wk1, const float* __restrict__ bk1,
    const float* __restrict__ wv1, const float* __restrict__ bv1,
    const float* __restrict__ ws1, const float* __restrict__ bs1,
    const float* __restrict__ wq2, const float* __restrict__ bq2,
    const float* __restrict__ wk2, const float* __restrict__ bk2,
    const float* __restrict__ wv2, const float* __restrict__ bv2,
    const float* __restrict__ ws2, const float* __restrict__ bs2,
    unsigned short* __restrict__ wt1h, unsigned short* __restrict__ wt1l,
    float* __restrict__ bias1,
    unsigned short* __restrict__ wt2h, unsigned short* __restrict__ wt2l,
    float* __restrict__ bias2,
    const int* __restrict__ dst, int* __restrict__ deg, int E)
{
    const int bx = blockIdx.x;
    const int t = threadIdx.x;
    if (bx >= 832) {                       // histogram part
        int e = (bx - 832) * 256 + t;
        if (e < E) atomicAdd(&deg[dst[e]], 1);
        return;
    }
    const int layer = (bx >= 416) ? 1 : 0;
    const int c = bx - layer * 416;
    const int L = layer ? 32 : 128;
    if (t >= L) return;
    const float* w; const float* b; int cc, ncols;
    if (c < 384) {
        int m = c >> 7; cc = c & 127; ncols = 128;
        if (layer == 0) {
            w = (m == 0) ? wq1 : ((m == 1) ? wk1 : wv1);
            b = (m == 0) ? bq1 : ((m == 1) ? bk1 : bv1);
        } else {
            w = (m == 0) ? wq2 : ((m == 1) ? wk2 : wv2);
            b = (m == 0) ? bq2 : ((m == 1) ? bk2 : bv2);
        }
    } else {
        cc = c - 384; ncols = 32;
        w = layer ? ws2 : ws1; b = layer ? bs2 : bs1;
    }
    unsigned short* wh = layer ? wt2h : wt1h;
    unsigned short* wl = layer ? wt2l : wt1l;
    float* bias = layer ? bias2 : bias1;
    const float QSCL = 0.17677669529663687f * 1.4426950408889634f;
    const float f = (c < 128) ? QSCL : 1.0f;
    float val = w[t * ncols + cc] * f;
    unsigned short h = f2bf(val);
    wh[c * L + t] = h;
    wl[c * L + t] = f2bf(val - bf2f(h));
    if (t == 0) bias[c] = b[cc] * f;
}

// -------- single-kernel CSR prefix scan (replaces scan_part/tops/final) ----
// One 1024-thread block walks N in 4096-element chunks with a carried
// offset; also zero-fills the perm prefetch pad. ~13 iterations for N=50K.
__global__ __launch_bounds__(1024) void scan_all(
    const int* __restrict__ deg, int* __restrict__ rowptr,
    int* __restrict__ cursor, int N, int* __restrict__ perm, int E)
{
    __shared__ int woff[16];
    const int tid = threadIdx.x, lane = tid & 63, w = tid >> 6;
    if (tid < 48) perm[E + tid] = 0;
    int carry = 0;
    for (int base = 0; base < N; base += 4096) {
        const int i0 = base + tid * 4;
        int v0 = (i0     < N) ? deg[i0]     : 0;
        int v1 = (i0 + 1 < N) ? deg[i0 + 1] : 0;
        int v2 = (i0 + 2 < N) ? deg[i0 + 2] : 0;
        int v3 = (i0 + 3 < N) ? deg[i0 + 3] : 0;
        int ts = v0 + v1 + v2 + v3;
        int inc = ts;
#pragma unroll
        for (int off = 1; off < 64; off <<= 1) {
            int t = __shfl_up(inc, off, 64);
            if (lane >= off) inc += t;
        }
        if (lane == 63) woff[w] = inc;
        __syncthreads();
        int wpre = 0, btot = 0;
#pragma unroll
        for (int k = 0; k < 16; k++) {
            int v = woff[k];
            if (k < w) wpre += v;
            btot += v;
        }
        int exc = carry + wpre + inc - ts;
        int p0 = exc, p1 = exc + v0, p2 = p1 + v1, p3 = p2 + v2;
        if (i0     < N) { rowptr[i0]     = p0; cursor[i0]     = p0; }
        if (i0 + 1 < N) { rowptr[i0 + 1] = p1; cursor[i0 + 1] = p1; }
        if (i0 + 2 < N) { rowptr[i0 + 2] = p2; cursor[i0 + 2] = p2; }
        if (i0 + 3 < N) { rowptr[i0 + 3] = p3; cursor[i0 + 3] = p3; }
        carry += btot;
        __syncthreads();
    }
    if (tid == 0) rowptr[N] = carry;
}

// -------- fused: layer-1 projection (blocks 0..2*NB-1) + CSR fill ----------
// R7 form exactly (empirical minimum: R5 sep=366, R7=352.4, R8=364, R9=367).
// proj part: 8-wave blocks, 256-node tiles, double-buffered LDS x-staging.
// fill part: 512 thr, 1 edge/thread at grid tail.
__global__ __launch_bounds__(512) void proj1_fill(
    const float* __restrict__ xin,
    const unsigned short* __restrict__ wt_hi,
    const unsigned short* __restrict__ wt_lo,
    const float* __restrict__ bias,
    float* __restrict__ q, unsigned short* __restrict__ kvp,
    float* __restrict__ skip, int N, int projNB,
    const int* __restrict__ src, const int* __restrict__ dst,
    int* __restrict__ cursor, int* __restrict__ perm, int E)
{
    constexpr int L = 128;
    constexpr int LP = L + 8;            // ushort pad
    constexpr int KS = L / 32;
    constexpr int ELEMS = 32 * (L / 4);  // float4 slots per 32-row tile
    constexpr int SI = (ELEMS + 511) / 512;
    __shared__ unsigned short xh[2][32 * LP];
    __shared__ unsigned short xl[2][32 * LP];
    __shared__ float scr[8][32 * 36];

    const int bx = blockIdx.x;
    const int tid = threadIdx.x;
    if (bx >= projNB * 2) {              // CSR fill part
        int e = (bx - projNB * 2) * 512 + tid;
        if (e < E) {
            int pos = atomicAdd(&cursor[dst[e]], 1);
            perm[pos] = src[e];
        }
        return;
    }

    const int lane = tid & 63, w = tid >> 6;   // w: 0..7
    const int li = lane & 15, quad = lane >> 4;
    const int slot = __builtin_amdgcn_readfirstlane((bx & 1) * 8 + w);
    const bool hasT = slot < 13;

    int t0 = 24, t1 = 25;
    if (slot < 4)       { t0 = slot * 2; t1 = t0 + 1; }
    else if (slot < 12) { t0 = 4 + slot; t1 = 12 + slot; }   // k=8+i, v=16+i

    short8 Ah[2][KS], Al[2][KS];
    float bias_r[2][4];
    if (hasT) {
#pragma unroll
        for (int ti = 0; ti < 2; ti++) {
            int tt = ti ? t1 : t0;
#pragma unroll
            for (int ks = 0; ks < KS; ks++) {
                long off = (long)(tt * 16 + li) * L + ks * 32 + quad * 8;
                Ah[ti][ks] = *(const short8*)(wt_hi + off);
                Al[ti][ks] = *(const short8*)(wt_lo + off);
            }
#pragma unroll
            for (int r = 0; r < 4; r++)
                bias_r[ti][r] = bias[tt * 16 + quad * 4 + r];
        }
    }

    const int nb0 = (bx >> 1) * 256;
    float* myscr = scr[w];
    unsigned int* su = (unsigned int*)myscr;

    float4 xv[SI];
    auto issue_loads = [&](int c) {
#pragma unroll
        for (int s = 0; s < SI; s++) {
            int f = s * 512 + tid;
            if (f < ELEMS) {
                int row = f / (L / 4), c4 = (f - row * (L / 4)) * 4;
                int n = nb0 + c * 32 + row;
                xv[s] = (n < N) ? *(const float4*)(xin + (long)n * L + c4)
                                : make_float4(0.f, 0.f, 0.f, 0.f);
            }
        }
    };
    auto cvt_store = [&](int buf) {
#pragma unroll
        for (int s = 0; s < SI; s++) {
            int f = s * 512 + tid;
            if (f < ELEMS) {
                int row = f / (L / 4), c4 = (f - row * (L / 4)) * 4;
                unsigned short h0 = f2bf(xv[s].x), h1 = f2bf(xv[s].y),
                               h2 = f2bf(xv[s].z), h3 = f2bf(xv[s].w);
                ushort4v hs = {h0, h1, h2, h3};
                ushort4v ls = {f2bf(xv[s].x - bf2f(h0)), f2bf(xv[s].y - bf2f(h1)),
                               f2bf(xv[s].z - bf2f(h2)), f2bf(xv[s].w - bf2f(h3))};
                *(ushort4v*)(xh[buf] + row * LP + c4) = hs;
                *(ushort4v*)(xl[buf] + row * LP + c4) = ls;
            }
        }
    };

    issue_loads(0);
    cvt_store(0);
    __syncthreads();

    for (int c = 0; c < 8; c++) {
        if (c < 7) issue_loads(c + 1);
        const int n0c = nb0 + c * 32;
        if (hasT) {
            const int buf = c & 1;
#pragma unroll
            for (int half = 0; half < 2; half++) {
                short8 Bh[KS], Bl[KS];
#pragma unroll
                for (int ks = 0; ks < KS; ks++) {
                    int off = (half * 16 + li) * LP + ks * 32 + quad * 8;
                    Bh[ks] = *(const short8*)(xh[buf] + off);
                    Bl[ks] = *(const short8*)(xl[buf] + off);
                }
                floatx4 accv[2];
#pragma unroll
                for (int ti = 0; ti < 2; ti++) {
                    floatx4 acc = {0.f, 0.f, 0.f, 0.f};
#pragma unroll
                    for (int ks = 0; ks < KS; ks++) {
                        acc = __builtin_amdgcn_mfma_f32_16x16x32_bf16(Ah[ti][ks], Bh[ks], acc, 0, 0, 0);
                        acc = __builtin_amdgcn_mfma_f32_16x16x32_bf16(Ah[ti][ks], Bl[ks], acc, 0, 0, 0);
                        acc = __builtin_amdgcn_mfma_f32_16x16x32_bf16(Al[ti][ks], Bh[ks], acc, 0, 0, 0);
                    }
#pragma unroll
                    for (int r = 0; r < 4; r++) acc[r] += bias_r[ti][r];
                    accv[ti] = acc;
                }
                const int row = half * 16 + li;
                if (slot < 4 || slot == 12) {
                    *(floatx4*)(myscr + row * 36 + quad * 4)      = accv[0];
                    *(floatx4*)(myscr + row * 36 + 16 + quad * 4) = accv[1];
                } else {
                    unsigned int k01 = (unsigned int)f2bf(accv[0][0]) | ((unsigned int)f2bf(accv[0][1]) << 16);
                    unsigned int k23 = (unsigned int)f2bf(accv[0][2]) | ((unsigned int)f2bf(accv[0][3]) << 16);
                    unsigned int v01 = (unsigned int)f2bf(accv[1][0]) | ((unsigned int)f2bf(accv[1][1]) << 16);
                    unsigned int v23 = (unsigned int)f2bf(accv[1][2]) | ((unsigned int)f2bf(accv[1][3]) << 16);
                    uint4 pk = make_uint4(k01, v01, k23, v23);
                    *(uint4*)(su + row * 20 + quad * 4) = pk;
                }
            }
            if (slot < 4) {
#pragma unroll
                for (int it = 0; it < 4; it++) {
                    int idx = it * 64 + lane;
                    int nl = idx >> 3, seg = idx & 7;
                    int node = n0c + nl;
                    if (node < N) {
                        floatx4 vv = *(floatx4*)(myscr + nl * 36 + seg * 4);
                        *(floatx4*)(q + (long)node * 128 + slot * 32 + seg * 4) = vv;
                    }
                }
            } else if (slot == 12) {
#pragma unroll
                for (int it = 0; it < 4; it++) {
                    int idx = it * 64 + lane;
                    int nl = idx >> 3, seg = idx & 7;
                    int node = n0c + nl;
                    if (node < N) {
                        floatx4 vv = *(floatx4*)(myscr + nl * 36 + seg * 4);
                        *(floatx4*)(skip + (long)node * 32 + seg * 4) = vv;
                    }
                }
            } else {
                const int i = slot - 4;
#pragma unroll
                for (int it = 0; it < 2; it++) {
                    int idx = it * 64 + lane;
                    int nl = idx >> 2, part = idx & 3;
                    int node = n0c + nl;
                    if (node < N) {
                        uint4 vv = *(uint4*)(su + nl * 20 + part * 4);
                        *(uint4*)((unsigned int*)(kvp + (long)node * 256) + i * 16 + part * 4) = vv;
                    }
                }
            }
        }
        __syncthreads();
        if (c < 7) cvt_store((c + 1) & 1);
        __syncthreads();
    }
}

// ---------------- K1 (layer 2 only): MFMA projection (R7 form) -------------
template <int L>
__global__ __launch_bounds__(512) void proj_mfma(
    const float* __restrict__ xin,
    const unsigned short* __restrict__ wt_hi,
    const unsigned short* __restrict__ wt_lo,
    const float* __restrict__ bias,
    float* __restrict__ q, unsigned short* __restrict__ kvp,
    float* __restrict__ skip, int N)
{
    constexpr int LP = L + 8;            // ushort pad
    constexpr int KS = L / 32;
    constexpr int ELEMS = 32 * (L / 4);  // float4 slots per 32-row tile
    constexpr int SI = (ELEMS + 511) / 512;
    __shared__ unsigned short xh[2][32 * LP];
    __shared__ unsigned short xl[2][32 * LP];
    __shared__ float scr[8][32 * 36];
    const int tid = threadIdx.x, lane = tid & 63, w = tid >> 6;   // w: 0..7
    const int li = lane & 15, quad = lane >> 4;
    const int slot = __builtin_amdgcn_readfirstlane(blockIdx.y * 8 + w);
    const bool hasT = slot < 13;

    int t0 = 24, t1 = 25;
    if (slot < 4)       { t0 = slot * 2; t1 = t0 + 1; }
    else if (slot < 12) { t0 = 4 + slot; t1 = 12 + slot; }   // k=8+i, v=16+i

    short8 Ah[2][KS], Al[2][KS];
    float bias_r[2][4];
    if (hasT) {
#pragma unroll
        for (int ti = 0; ti < 2; ti++) {
            int tt = ti ? t1 : t0;
#pragma unroll
            for (int ks = 0; ks < KS; ks++) {
                long off = (long)(tt * 16 + li) * L + ks * 32 + quad * 8;
                Ah[ti][ks] = *(const short8*)(wt_hi + off);
                Al[ti][ks] = *(const short8*)(wt_lo + off);
            }
#pragma unroll
            for (int r = 0; r < 4; r++)
                bias_r[ti][r] = bias[tt * 16 + quad * 4 + r];
        }
    }

    const int nb0 = blockIdx.x * 256;
    float* myscr = scr[w];
    unsigned int* su = (unsigned int*)myscr;

    float4 xv[SI];
    auto issue_loads = [&](int c) {
#pragma unroll
        for (int s = 0; s < SI; s++) {
            int f = s * 512 + tid;
            if (f < ELEMS) {
                int row = f / (L / 4), c4 = (f - row * (L / 4)) * 4;
                int n = nb0 + c * 32 + row;
                xv[s] = (n < N) ? *(const float4*)(xin + (long)n * L + c4)
                                : make_float4(0.f, 0.f, 0.f, 0.f);
            }
        }
    };
    auto cvt_store = [&](int buf) {
#pragma unroll
        for (int s = 0; s < SI; s++) {
            int f = s * 512 + tid;
            if (f < ELEMS) {
                int row = f / (L / 4), c4 = (f - row * (L / 4)) * 4;
                unsigned short h0 = f2bf(xv[s].x), h1 = f2bf(xv[s].y),
                               h2 = f2bf(xv[s].z), h3 = f2bf(xv[s].w);
                ushort4v hs = {h0, h1, h2, h3};
                ushort4v ls = {f2bf(xv[s].x - bf2f(h0)), f2bf(xv[s].y - bf2f(h1)),
                               f2bf(xv[s].z - bf2f(h2)), f2bf(xv[s].w - bf2f(h3))};
                *(ushort4v*)(xh[buf] + row * LP + c4) = hs;
                *(ushort4v*)(xl[buf] + row * LP + c4) = ls;
            }
        }
    };

    issue_loads(0);
    cvt_store(0);
    __syncthreads();

    for (int c = 0; c < 8; c++) {
        if (c < 7) issue_loads(c + 1);
        const int n0c = nb0 + c * 32;
        if (hasT) {
            const int buf = c & 1;
#pragma unroll
            for (int half = 0; half < 2; half++) {
                short8 Bh[KS], Bl[KS];
#pragma unroll
                for (int ks = 0; ks < KS; ks++) {
                    int off = (half * 16 + li) * LP + ks * 32 + quad * 8;
                    Bh[ks] = *(const short8*)(xh[buf] + off);
                    Bl[ks] = *(const short8*)(xl[buf] + off);
                }
                floatx4 accv[2];
#pragma unroll
                for (int ti = 0; ti < 2; ti++) {
                    floatx4 acc = {0.f, 0.f, 0.f, 0.f};
#pragma unroll
                    for (int ks = 0; ks < KS; ks++) {
                        acc = __builtin_amdgcn_mfma_f32_16x16x32_bf16(Ah[ti][ks], Bh[ks], acc, 0, 0, 0);
                        acc = __builtin_amdgcn_mfma_f32_16x16x32_bf16(Ah[ti][ks], Bl[ks], acc, 0, 0, 0);
                        acc = __builtin_amdgcn_mfma_f32_16x16x32_bf16(Al[ti][ks], Bh[ks], acc, 0, 0, 0);
                    }
#pragma unroll
                    for (int r = 0; r < 4; r++) acc[r] += bias_r[ti][r];
                    accv[ti] = acc;
                }
                const int row = half * 16 + li;
                if (slot < 4 || slot == 12) {
                    *(floatx4*)(myscr + row * 36 + quad * 4)      = accv[0];
                    *(floatx4*)(myscr + row * 36 + 16 + quad * 4) = accv[1];
                } else {
                    unsigned int k01 = (unsigned int)f2bf(accv[0][0]) | ((unsigned int)f2bf(accv[0][1]) << 16);
                    unsigned int k23 = (unsigned int)f2bf(accv[0][2]) | ((unsigned int)f2bf(accv[0][3]) << 16);
                    unsigned int v01 = (unsigned int)f2bf(accv[1][0]) | ((unsigned int)f2bf(accv[1][1]) << 16);
                    unsigned int v23 = (unsigned int)f2bf(accv[1][2]) | ((unsigned int)f2bf(accv[1][3]) << 16);
                    uint4 pk = make_uint4(k01, v01, k23, v23);
                    *(uint4*)(su + row * 20 + quad * 4) = pk;
                }
            }
            if (slot < 4) {
#pragma unroll
                for (int it = 0; it < 4; it++) {
                    int idx = it * 64 + lane;
                    int nl = idx >> 3, seg = idx & 7;
                    int node = n0c + nl;
                    if (node < N) {
                        floatx4 vv = *(floatx4*)(myscr + nl * 36 + seg * 4);
                        *(floatx4*)(q + (long)node * 128 + slot * 32 + seg * 4) = vv;
                    }
                }
            } else if (slot == 12) {
#pragma unroll
                for (int it = 0; it < 4; it++) {
                    int idx = it * 64 + lane;
                    int nl = idx >> 3, seg = idx & 7;
                    int node = n0c + nl;
                    if (node < N) {
                        floatx4 vv = *(floatx4*)(myscr + nl * 36 + seg * 4);
                        *(floatx4*)(skip + (long)node * 32 + seg * 4) = vv;
                    }
                }
            } else {
                const int i = slot - 4;
#pragma unroll
                for (int it = 0; it < 2; it++) {
                    int idx = it * 64 + lane;
                    int nl = idx >> 2, part = idx & 3;
                    int node = n0c + nl;
                    if (node < N) {
                        uint4 vv = *(uint4*)(su + nl * 20 + part * 4);
                        *(uint4*)((unsigned int*)(kvp + (long)node * 256) + i * 16 + part * 4) = vv;
                    }
                }
            }
        }
        __syncthreads();
        if (c < 7) cvt_store((c + 1) & 1);
        __syncthreads();
    }
}

// ---------------- K2: fused attention, 3-group rotated pipeline ------------
// FROZEN (R5 form). Five structural variants (R0/R2/R3/R4/R6) all pin the
// gather miss path at 3.2-3.45 TB/s => ~62us is this algorithm's floor.
template <bool FUSE_CLS>
__global__ __launch_bounds__(256) void attn_kernel(
    const float* __restrict__ q, const unsigned short* __restrict__ kvp,
    const int* __restrict__ rowptr, const int* __restrict__ perm,
    const float* __restrict__ skip, float* __restrict__ h,
    const float* __restrict__ wc, const float* __restrict__ bc,
    float* __restrict__ out, int N, int E)
{
    __shared__ float hrow[4][32];
    const int tid = threadIdx.x;
    const int wid = (blockIdx.x * 256 + tid) >> 6;
    const int wv = (tid >> 6) & 3;
    const int lane = tid & 63;
    if (wid >= N) return;
    const int d = __builtin_amdgcn_readfirstlane(wid);
    const int eh = lane >> 5;
    const int sl = lane & 31;
    const int hh = sl >> 3;
    const int g  = sl & 7;
    const unsigned dby = (unsigned)(hh * 64 + g * 8) * 2u;   // byte offset in 512B row
    const char* __restrict__ kvb = (const char*)kvp;
    const float4 q4 = *(const float4*)(q + (long)d * 128 + hh * 32 + g * 4);

    const int beg = rowptr[d], end = rowptr[d + 1];
    const int n = end - beg;
    const int na = (n + 1) >> 1;          // larger half (eh=0)
    const int nmin = n - na;              // smaller half (eh=1)
    const int my_off = beg + (eh ? na : 0);
    const int my_cnt = eh ? nmin : na;
    const int* __restrict__ pp = perm + my_off;   // perm has 48-entry zero pad

    float den = 0.f;
    float o0 = 0.f, o1 = 0.f, o2 = 0.f, o3 = 0.f;

    auto kvld = [&](int s) -> uint4 {
        return *(const uint4*)(kvb + ((((unsigned)s) << 9) + dby));
    };

    // ---- prime: kv for edges 0..11, perm for edges 12..23 ----
    uint4 A0, A1, A2, A3, B0, B1, B2, B3, C0, C1, C2, C3;
    int PA0, PA1, PA2, PA3, PB0, PB1, PB2, PB3, PC0, PC1, PC2, PC3;
    {
        int i0 = pp[0], i1 = pp[1], i2  = pp[2],  i3  = pp[3];
        int i4 = pp[4], i5 = pp[5], i6  = pp[6],  i7  = pp[7];
        int i8 = pp[8], i9 = pp[9], i10 = pp[10], i11 = pp[11];
        PA0 = pp[12]; PA1 = pp[13]; PA2 = pp[14]; PA3 = pp[15];
        PB0 = pp[16]; PB1 = pp[17]; PB2 = pp[18]; PB3 = pp[19];
        PC0 = pp[20]; PC1 = pp[21]; PC2 = pp[22]; PC3 = pp[23];
        A0 = kvld(i0); A1 = kvld(i1); A2 = kvld(i2);  A3 = kvld(i3);
        B0 = kvld(i4); B1 = kvld(i5); B2 = kvld(i6);  B3 = kvld(i7);
        C0 = kvld(i8); C1 = kvld(i9); C2 = kvld(i10); C3 = kvld(i11);
    }

    // group compute: 4 edge-slots (x2 halves) from G0..G3, base edge jb
    auto grp = [&](const uint4& G0, const uint4& G1, const uint4& G2,
                   const uint4& G3, int jb, auto mc) {
        constexpr bool MASKED = decltype(mc)::value;
        float p0 = q4.x * blo(G0.x) + q4.y * bhi(G0.x) + q4.z * blo(G0.z) + q4.w * bhi(G0.z);
        float p1 = q4.x * blo(G1.x) + q4.y * bhi(G1.x) + q4.z * blo(G1.z) + q4.w * bhi(G1.z);
        float p2 = q4.x * blo(G2.x) + q4.y * bhi(G2.x) + q4.z * blo(G2.z) + q4.w * bhi(G2.z);
        float p3 = q4.x * blo(G3.x) + q4.y * bhi(G3.x) + q4.z * blo(G3.z) + q4.w * bhi(G3.z);
        p0 = red8(p0); p1 = red8(p1); p2 = red8(p2); p3 = red8(p3);
        p0 = fminf(p0, 60.f); p1 = fminf(p1, 60.f);
        p2 = fminf(p2, 60.f); p3 = fminf(p3, 60.f);
        if (MASKED) {
            p0 = (jb + 0 < my_cnt) ? p0 : -INFINITY;
            p1 = (jb + 1 < my_cnt) ? p1 : -INFINITY;
            p2 = (jb + 2 < my_cnt) ? p2 : -INFINITY;
            p3 = (jb + 3 < my_cnt) ? p3 : -INFINITY;
        }
        const float w0 = EXP2F(p0), w1 = EXP2F(p1);
        const float w2 = EXP2F(p2), w3 = EXP2F(p3);
        den += (w0 + w1) + (w2 + w3);
        o0 += w0 * blo(G0.y) + w1 * blo(G1.y) + w2 * blo(G2.y) + w3 * blo(G3.y);
        o1 += w0 * bhi(G0.y) + w1 * bhi(G1.y) + w2 * bhi(G2.y) + w3 * bhi(G3.y);
        o2 += w0 * blo(G0.w) + w1 * blo(G1.w) + w2 * blo(G2.w) + w3 * blo(G3.w);
        o3 += w0 * bhi(G0.w) + w1 * bhi(G1.w) + w2 * bhi(G2.w) + w3 * bhi(G3.w);
    };

    int j = 0;
    for (; j + 12 <= nmin; j += 12) {
        grp(A0, A1, A2, A3, j, BC<false>{});
        A0 = kvld(PA0); A1 = kvld(PA1); A2 = kvld(PA2); A3 = kvld(PA3);
        PA0 = pp[j + 24]; PA1 = pp[j + 25]; PA2 = pp[j + 26]; PA3 = pp[j + 27];
        grp(B0, B1, B2, B3, j + 4, BC<false>{});
        B0 = kvld(PB0); B1 = kvld(PB1); B2 = kvld(PB2); B3 = kvld(PB3);
        PB0 = pp[j + 28]; PB1 = pp[j + 29]; PB2 = pp[j + 30]; PB3 = pp[j + 31];
        grp(C0, C1, C2, C3, j + 8, BC<false>{});
        C0 = kvld(PC0); C1 = kvld(PC1); C2 = kvld(PC2); C3 = kvld(PC3);
        PC0 = pp[j + 32]; PC1 = pp[j + 33]; PC2 = pp[j + 34]; PC3 = pp[j + 35];
    }
    // masked tail: at most 12 remaining edge-slots per half (na <= nmin+1)
    if (j < na) {
        grp(A0, A1, A2, A3, j, BC<true>{});
        if (j + 4 < na) grp(B0, B1, B2, B3, j + 4, BC<true>{});
        if (j + 8 < na) grp(C0, C1, C2, C3, j + 8, BC<true>{});
    }

    // merge the two halves (pure sums — no max bookkeeping)
    den += __shfl_xor(den, 32);
    o0 += __shfl_xor(o0, 32);
    o1 += __shfl_xor(o1, 32);
    o2 += __shfl_xor(o2, 32);
    o3 += __shfl_xor(o3, 32);

    const float inv = 1.f / (den + 1e-16f);
    o0 *= inv; o1 *= inv; o2 *= inv; o3 *= inv;
    // head mean: sum over head groups (xor 8 via DPP, then xor 16), /4
    o0 = xor8add(o0); o1 = xor8add(o1);
    o2 = xor8add(o2); o3 = xor8add(o3);
    o0 += __shfl_xor(o0, 16); o1 += __shfl_xor(o1, 16);
    o2 += __shfl_xor(o2, 16); o3 += __shfl_xor(o3, 16);

    if (lane < 8) {
        float4 sk = *(const float4*)(skip + (long)d * 32 + g * 4);
        float r0 = 0.25f * o0 + sk.x;
        float r1 = 0.25f * o1 + sk.y;
        float r2 = 0.25f * o2 + sk.z;
        float r3 = 0.25f * o3 + sk.w;
        r0 = r0 > 0.f ? r0 : 0.f;
        r1 = r1 > 0.f ? r1 : 0.f;
        r2 = r2 > 0.f ? r2 : 0.f;
        r3 = r3 > 0.f ? r3 : 0.f;
        if (FUSE_CLS) {
            *(float4*)&hrow[wv][g * 4] = make_float4(r0, r1, r2, r3);
        } else {
            *(float4*)(h + (long)d * 32 + g * 4) = make_float4(r0, r1, r2, r3);
        }
    }
    if (FUSE_CLS) {
        __builtin_amdgcn_wave_barrier();   // wave-internal LDS ordering (no HW cost)
        if (lane < 40) {
            float acc = bc[lane];
#pragma unroll
            for (int l = 0; l < 32; ++l)
                acc = fmaf(hrow[wv][l], wc[l * 40 + lane], acc);
            out[(long)d * 40 + lane] = acc;
        }
    }
}

extern "C" void kernel_launch(void* const* d_in, const int* in_sizes, int n_in,
                              void* d_out, int out_size, void* d_ws, size_t ws_size,
                              hipStream_t stream)
{
    const float* x   = (const float*)d_in[0];
    const int* ei    = (const int*)d_in[1];
    const float* wq1 = (const float*)d_in[2];  const float* bq1 = (const float*)d_in[3];
    const float* wk1 = (const float*)d_in[4];  const float* bk1 = (const float*)d_in[5];
    const float* wv1 = (const float*)d_in[6];  const float* bv1 = (const float*)d_in[7];
    const float* ws1 = (const float*)d_in[8];  const float* bs1 = (const float*)d_in[9];
    const float* wq2 = (const float*)d_in[10]; const float* bq2 = (const float*)d_in[11];
    const float* wk2 = (const float*)d_in[12]; const float* bk2 = (const float*)d_in[13];
    const float* wv2 = (const float*)d_in[14]; const float* bv2 = (const float*)d_in[15];
    const float* ws2 = (const float*)d_in[16]; const float* bs2 = (const float*)d_in[17];
    const float* wc  = (const float*)d_in[18]; const float* bc  = (const float*)d_in[19];

    const int N = in_sizes[0] / 128;   // 50000
    const int E = in_sizes[1] / 2;     // 800000
    const int* src = ei;
    const int* dst = ei + E;

    // workspace layout (bytes, 256-aligned chunks)
    char* p = (char*)d_ws;
    auto take = [&](size_t bytes) { char* r = p; p += (bytes + 255) & ~(size_t)255; return r; };
    float* q             = (float*)take((size_t)N * 128 * 4);
    unsigned short* kvp  = (unsigned short*)take((size_t)N * 256 * 2);
    float* skip          = (float*)take((size_t)N * 32 * 4);
    float* h1            = (float*)take((size_t)N * 32 * 4);
    unsigned short* wt1h = (unsigned short*)take(416 * 128 * 2);
    unsigned short* wt1l = (unsigned short*)take(416 * 128 * 2);
    unsigned short* wt2h = (unsigned short*)take(416 * 32 * 2);
    unsigned short* wt2l = (unsigned short*)take(416 * 32 * 2);
    float* bias1         = (float*)take(416 * 4);
    float* bias2         = (float*)take(416 * 4);
    int* deg             = (int*)take((size_t)N * 4);
    int* rowptr          = (int*)take((size_t)(N + 1) * 4);
    int* cursor          = (int*)take((size_t)N * 4);
    int* perm            = (int*)take((size_t)(E + 48) * 4);   // +48 zero pad

    const int projNB   = (N + 255) / 256;               // 196
    const int eGrid256 = (E + 255) / 256;               // 3125 (hist part)
    const int eGrid512 = (E + 511) / 512;               // 1563 (fill part)
    const int attnGrid = (N + 3) / 4;                   // 4 waves/block

    // ---------------- prep: [memset deg] -> [wprep ∥ hist] -> scan ---------
    hipMemsetAsync(deg, 0, (size_t)N * 4, stream);
    wprep_hist<<<832 + eGrid256, 256, 0, stream>>>(
        wq1, bq1, wk1, bk1, wv1, bv1, ws1, bs1,
        wq2, bq2, wk2, bk2, wv2, bv2, ws2, bs2,
        wt1h, wt1l, bias1, wt2h, wt2l, bias2,
        dst, deg, E);
    scan_all<<<1, 1024, 0, stream>>>(deg, rowptr, cursor, N, perm, E);

    // ---------------- [proj1 ∥ fill] -> attn1 ------------------------------
    proj1_fill<<<projNB * 2 + eGrid512, 512, 0, stream>>>(
        x, wt1h, wt1l, bias1, q, kvp, skip, N, projNB,
        src, dst, cursor, perm, E);
    attn_kernel<false><<<attnGrid, 256, 0, stream>>>(q, kvp, rowptr, perm, skip, h1,
                                                     wc, bc, (float*)d_out, N, E);

    // ---------------- layer 2 (classifier fused into attn epilogue) --------
    proj_mfma<32><<<dim3(projNB, 2), 512, 0, stream>>>(h1, wt2h, wt2l, bias2,
                                                       q, kvp, skip, N);
    attn_kernel<true><<<attnGrid, 256, 0, stream>>>(q, kvp, rowptr, perm, skip, h1,
                                                    wc, bc, (float*)d_out, N, E);
}

// Round 11
// 349.085 us; speedup vs baseline: 1.0782x; 1.0782x over previous
//
#include <hip/hip_runtime.h>
#include <hip/hip_bf16.h>

typedef __attribute__((ext_vector_type(8))) short short8;       // 8 bf16 (A/B frag)
typedef __attribute__((ext_vector_type(4))) float floatx4;      // C/D frag
typedef __attribute__((ext_vector_type(4))) unsigned short ushort4v;

__device__ inline unsigned short f2bf(float x) {                 // RNE f32->bf16 bits
    unsigned int u = __float_as_uint(x);
    u += 0x7FFFu + ((u >> 16) & 1u);
    return (unsigned short)(u >> 16);
}
__device__ inline float bf2f(unsigned short h) {
    return __uint_as_float(((unsigned int)h) << 16);
}
__device__ inline float blo(unsigned int u) { return __uint_as_float(u << 16); }
__device__ inline float bhi(unsigned int u) { return __uint_as_float(u & 0xFFFF0000u); }

#if defined(__has_builtin)
#if __has_builtin(__builtin_amdgcn_exp2f)
#define EXP2F(x) __builtin_amdgcn_exp2f(x)
#else
#define EXP2F(x) exp2f(x)
#endif
#if __has_builtin(__builtin_amdgcn_update_dpp)
#define HAVE_DPP 1
#endif
#else
#define EXP2F(x) exp2f(x)
#endif

// DPP butterfly add: x + shuffle(x) — pure VALU, no LDS pipe, no lgkmcnt wait.
#ifdef HAVE_DPP
template <int CTRL>
__device__ __forceinline__ float dppadd(float x) {
    int s = __builtin_amdgcn_update_dpp(0, __float_as_int(x), CTRL, 0xf, 0xf, true);
    return x + __int_as_float(s);
}
// sum over the 8 lanes of a g-octet (lane bits 0..2): xor1, xor2, xor7-mirror
__device__ __forceinline__ float red8(float x) {
    x = dppadd<0xB1>(x);    // quad_perm [1,0,3,2]  = xor 1
    x = dppadd<0x4E>(x);    // quad_perm [2,3,0,1]  = xor 2
    x = dppadd<0x141>(x);   // row_half_mirror      = xor 7 (valid: quads uniform)
    return x;
}
__device__ __forceinline__ float xor8add(float x) {
    return dppadd<0x128>(x);   // row_ror:8 = xor 8 within 16-lane row
}
#else
__device__ __forceinline__ float red8(float x) {
    x += __shfl_xor(x, 1); x += __shfl_xor(x, 2); x += __shfl_xor(x, 4);
    return x;
}
__device__ __forceinline__ float xor8add(float x) { return x + __shfl_xor(x, 8); }
#endif

template <bool B> struct BC { static constexpr bool value = B; };

// -------- fused: weight prep (blocks 0..831) + degree hist (blocks 832+) ---
__global__ __launch_bounds__(256) void wprep_hist(
    const float* __restrict__ wq1, const float* __restrict__ bq1,
    const float* __restrict__ wk1, const float* __restrict__ bk1,
    const float* __restrict__ wv1, const float* __restrict__ bv1,
    const float* __restrict__ ws1, const float* __restrict__ bs1,
    const float* __restrict__ wq2, const float* __restrict__ bq2,
    const float* __restrict__ wk2, const float* __restrict__ bk2,
    const float* __restrict__ wv2, const float* __restrict__ bv2,
    const float* __restrict__ ws2, const float* __restrict__ bs2,
    unsigned short* __restrict__ wt1h, unsigned short* __restrict__ wt1l,
    float* __restrict__ bias1,
    unsigned short* __restrict__ wt2h, unsigned short* __restrict__ wt2l,
    float* __restrict__ bias2,
    const int* __restrict__ dst, int* __restrict__ deg, int E)
{
    const int bx = blockIdx.x;
    const int t = threadIdx.x;
    if (bx >= 832) {                       // histogram part
        int e = (bx - 832) * 256 + t;
        if (e < E) atomicAdd(&deg[dst[e]], 1);
        return;
    }
    const int layer = (bx >= 416) ? 1 : 0;
    const int c = bx - layer * 416;
    const int L = layer ? 32 : 128;
    if (t >= L) return;
    const float* w; const float* b; int cc, ncols;
    if (c < 384) {
        int m = c >> 7; cc = c & 127; ncols = 128;
        if (layer == 0) {
            w = (m == 0) ? wq1 : ((m == 1) ? wk1 : wv1);
            b = (m == 0) ? bq1 : ((m == 1) ? bk1 : bv1);
        } else {
            w = (m == 0) ? wq2 : ((m == 1) ? wk2 : wv2);
            b = (m == 0) ? bq2 : ((m == 1) ? bk2 : bv2);
        }
    } else {
        cc = c - 384; ncols = 32;
        w = layer ? ws2 : ws1; b = layer ? bs2 : bs1;
    }
    unsigned short* wh = layer ? wt2h : wt1h;
    unsigned short* wl = layer ? wt2l : wt1l;
    float* bias = layer ? bias2 : bias1;
    const float QSCL = 0.17677669529663687f * 1.4426950408889634f;
    const float f = (c < 128) ? QSCL : 1.0f;
    float val = w[t * ncols + cc] * f;
    unsigned short h = f2bf(val);
    wh[c * L + t] = h;
    wl[c * L + t] = f2bf(val - bf2f(h));
    if (t == 0) bias[c] = b[cc] * f;
}

// hierarchical scan: block sums -> top scan (<=64 blocks) -> add-back
__global__ __launch_bounds__(256) void scan_part(
    const int* __restrict__ deg, int* __restrict__ bsum, int N)
{
    __shared__ int ws[4];
    const int base = blockIdx.x * 1024;
    const int tid = threadIdx.x, lane = tid & 63, w = tid >> 6;
    int s = 0;
#pragma unroll
    for (int j = 0; j < 4; j++) {
        int i = base + j * 256 + tid;
        if (i < N) s += deg[i];
    }
#pragma unroll
    for (int off = 1; off < 64; off <<= 1) s += __shfl_xor(s, off, 64);
    if (lane == 0) ws[w] = s;
    __syncthreads();
    if (tid == 0) bsum[blockIdx.x] = ws[0] + ws[1] + ws[2] + ws[3];
}

// also zero-fills the perm prefetch pad (48 ints past E) before fill runs
__global__ __launch_bounds__(64) void scan_tops(
    const int* __restrict__ bsum, int* __restrict__ boff,
    int* __restrict__ rowptr, int nb, int N,
    int* __restrict__ perm, int E)
{
    int lane = threadIdx.x;
    if (lane < 48) perm[E + lane] = 0;
    int v = (lane < nb) ? bsum[lane] : 0;
    int inc = v;
#pragma unroll
    for (int off = 1; off < 64; off <<= 1) {
        int t = __shfl_up(inc, off, 64);
        if (lane >= off) inc += t;
    }
    if (lane < nb) boff[lane] = inc - v;
    if (lane == 63) rowptr[N] = inc;
}

__global__ __launch_bounds__(256) void scan_final(
    const int* __restrict__ deg, const int* __restrict__ boff,
    int* __restrict__ rowptr, int* __restrict__ cursor, int N)
{
    __shared__ int woff[4];
    const int base = blockIdx.x * 1024;
    const int tid = threadIdx.x, lane = tid & 63, w = tid >> 6;
    const int i0 = base + tid * 4;
    int v0 = (i0     < N) ? deg[i0]     : 0;
    int v1 = (i0 + 1 < N) ? deg[i0 + 1] : 0;
    int v2 = (i0 + 2 < N) ? deg[i0 + 2] : 0;
    int v3 = (i0 + 3 < N) ? deg[i0 + 3] : 0;
    int ts = v0 + v1 + v2 + v3;
    int inc = ts;
#pragma unroll
    for (int off = 1; off < 64; off <<= 1) {
        int t = __shfl_up(inc, off, 64);
        if (lane >= off) inc += t;
    }
    if (lane == 63) woff[w] = inc;
    __syncthreads();
    int wpre = 0;
    if (w > 0) wpre += woff[0];
    if (w > 1) wpre += woff[1];
    if (w > 2) wpre += woff[2];
    int exc = boff[blockIdx.x] + wpre + inc - ts;
    int p0 = exc, p1 = exc + v0, p2 = p1 + v1, p3 = p2 + v2;
    if (i0     < N) { rowptr[i0]     = p0; cursor[i0]     = p0; }
    if (i0 + 1 < N) { rowptr[i0 + 1] = p1; cursor[i0 + 1] = p1; }
    if (i0 + 2 < N) { rowptr[i0 + 2] = p2; cursor[i0 + 2] = p2; }
    if (i0 + 3 < N) { rowptr[i0 + 3] = p3; cursor[i0 + 3] = p3; }
}

// -------- fused: layer-1 projection (blocks 0..2*NB-1) + CSR fill ----------
// Empirical minimum configuration (R7 = 352.4us): 8-wave blocks, 256-node
// tiles, double-buffered LDS x-staging; fill at grid tail. R8 (barrier-free),
// R9 (128-tile), R10 (scan consolidation) all regressed.
__global__ __launch_bounds__(512) void proj1_fill(
    const float* __restrict__ xin,
    const unsigned short* __restrict__ wt_hi,
    const unsigned short* __restrict__ wt_lo,
    const float* __restrict__ bias,
    float* __restrict__ q, unsigned short* __restrict__ kvp,
    float* __restrict__ skip, int N, int projNB,
    const int* __restrict__ src, const int* __restrict__ dst,
    int* __restrict__ cursor, int* __restrict__ perm, int E)
{
    constexpr int L = 128;
    constexpr int LP = L + 8;            // ushort pad
    constexpr int KS = L / 32;
    constexpr int ELEMS = 32 * (L / 4);  // float4 slots per 32-row tile
    constexpr int SI = (ELEMS + 511) / 512;
    __shared__ unsigned short xh[2][32 * LP];
    __shared__ unsigned short xl[2][32 * LP];
    __shared__ float scr[8][32 * 36];

    const int bx = blockIdx.x;
    const int tid = threadIdx.x;
    if (bx >= projNB * 2) {              // CSR fill part
        int e = (bx - projNB * 2) * 512 + tid;
        if (e < E) {
            int pos = atomicAdd(&cursor[dst[e]], 1);
            perm[pos] = src[e];
        }
        return;
    }

    const int lane = tid & 63, w = tid >> 6;   // w: 0..7
    const int li = lane & 15, quad = lane >> 4;
    const int slot = __builtin_amdgcn_readfirstlane((bx & 1) * 8 + w);
    const bool hasT = slot < 13;

    int t0 = 24, t1 = 25;
    if (slot < 4)       { t0 = slot * 2; t1 = t0 + 1; }
    else if (slot < 12) { t0 = 4 + slot; t1 = 12 + slot; }   // k=8+i, v=16+i

    short8 Ah[2][KS], Al[2][KS];
    float bias_r[2][4];
    if (hasT) {
#pragma unroll
        for (int ti = 0; ti < 2; ti++) {
            int tt = ti ? t1 : t0;
#pragma unroll
            for (int ks = 0; ks < KS; ks++) {
                long off = (long)(tt * 16 + li) * L + ks * 32 + quad * 8;
                Ah[ti][ks] = *(const short8*)(wt_hi + off);
                Al[ti][ks] = *(const short8*)(wt_lo + off);
            }
#pragma unroll
            for (int r = 0; r < 4; r++)
                bias_r[ti][r] = bias[tt * 16 + quad * 4 + r];
        }
    }

    const int nb0 = (bx >> 1) * 256;
    float* myscr = scr[w];
    unsigned int* su = (unsigned int*)myscr;

    float4 xv[SI];
    auto issue_loads = [&](int c) {
#pragma unroll
        for (int s = 0; s < SI; s++) {
            int f = s * 512 + tid;
            if (f < ELEMS) {
                int row = f / (L / 4), c4 = (f - row * (L / 4)) * 4;
                int n = nb0 + c * 32 + row;
                xv[s] = (n < N) ? *(const float4*)(xin + (long)n * L + c4)
                                : make_float4(0.f, 0.f, 0.f, 0.f);
            }
        }
    };
    auto cvt_store = [&](int buf) {
#pragma unroll
        for (int s = 0; s < SI; s++) {
            int f = s * 512 + tid;
            if (f < ELEMS) {
                int row = f / (L / 4), c4 = (f - row * (L / 4)) * 4;
                unsigned short h0 = f2bf(xv[s].x), h1 = f2bf(xv[s].y),
                               h2 = f2bf(xv[s].z), h3 = f2bf(xv[s].w);
                ushort4v hs = {h0, h1, h2, h3};
                ushort4v ls = {f2bf(xv[s].x - bf2f(h0)), f2bf(xv[s].y - bf2f(h1)),
                               f2bf(xv[s].z - bf2f(h2)), f2bf(xv[s].w - bf2f(h3))};
                *(ushort4v*)(xh[buf] + row * LP + c4) = hs;
                *(ushort4v*)(xl[buf] + row * LP + c4) = ls;
            }
        }
    };

    issue_loads(0);
    cvt_store(0);
    __syncthreads();

    for (int c = 0; c < 8; c++) {
        if (c < 7) issue_loads(c + 1);
        const int n0c = nb0 + c * 32;
        if (hasT) {
            const int buf = c & 1;
#pragma unroll
            for (int half = 0; half < 2; half++) {
                short8 Bh[KS], Bl[KS];
#pragma unroll
                for (int ks = 0; ks < KS; ks++) {
                    int off = (half * 16 + li) * LP + ks * 32 + quad * 8;
                    Bh[ks] = *(const short8*)(xh[buf] + off);
                    Bl[ks] = *(const short8*)(xl[buf] + off);
                }
                floatx4 accv[2];
#pragma unroll
                for (int ti = 0; ti < 2; ti++) {
                    floatx4 acc = {0.f, 0.f, 0.f, 0.f};
#pragma unroll
                    for (int ks = 0; ks < KS; ks++) {
                        acc = __builtin_amdgcn_mfma_f32_16x16x32_bf16(Ah[ti][ks], Bh[ks], acc, 0, 0, 0);
                        acc = __builtin_amdgcn_mfma_f32_16x16x32_bf16(Ah[ti][ks], Bl[ks], acc, 0, 0, 0);
                        acc = __builtin_amdgcn_mfma_f32_16x16x32_bf16(Al[ti][ks], Bh[ks], acc, 0, 0, 0);
                    }
#pragma unroll
                    for (int r = 0; r < 4; r++) acc[r] += bias_r[ti][r];
                    accv[ti] = acc;
                }
                const int row = half * 16 + li;
                if (slot < 4 || slot == 12) {
                    *(floatx4*)(myscr + row * 36 + quad * 4)      = accv[0];
                    *(floatx4*)(myscr + row * 36 + 16 + quad * 4) = accv[1];
                } else {
                    unsigned int k01 = (unsigned int)f2bf(accv[0][0]) | ((unsigned int)f2bf(accv[0][1]) << 16);
                    unsigned int k23 = (unsigned int)f2bf(accv[0][2]) | ((unsigned int)f2bf(accv[0][3]) << 16);
                    unsigned int v01 = (unsigned int)f2bf(accv[1][0]) | ((unsigned int)f2bf(accv[1][1]) << 16);
                    unsigned int v23 = (unsigned int)f2bf(accv[1][2]) | ((unsigned int)f2bf(accv[1][3]) << 16);
                    uint4 pk = make_uint4(k01, v01, k23, v23);
                    *(uint4*)(su + row * 20 + quad * 4) = pk;
                }
            }
            if (slot < 4) {
#pragma unroll
                for (int it = 0; it < 4; it++) {
                    int idx = it * 64 + lane;
                    int nl = idx >> 3, seg = idx & 7;
                    int node = n0c + nl;
                    if (node < N) {
                        floatx4 vv = *(floatx4*)(myscr + nl * 36 + seg * 4);
                        *(floatx4*)(q + (long)node * 128 + slot * 32 + seg * 4) = vv;
                    }
                }
            } else if (slot == 12) {
#pragma unroll
                for (int it = 0; it < 4; it++) {
                    int idx = it * 64 + lane;
                    int nl = idx >> 3, seg = idx & 7;
                    int node = n0c + nl;
                    if (node < N) {
                        floatx4 vv = *(floatx4*)(myscr + nl * 36 + seg * 4);
                        *(floatx4*)(skip + (long)node * 32 + seg * 4) = vv;
                    }
                }
            } else {
                const int i = slot - 4;
#pragma unroll
                for (int it = 0; it < 2; it++) {
                    int idx = it * 64 + lane;
                    int nl = idx >> 2, part = idx & 3;
                    int node = n0c + nl;
                    if (node < N) {
                        uint4 vv = *(uint4*)(su + nl * 20 + part * 4);
                        *(uint4*)((unsigned int*)(kvp + (long)node * 256) + i * 16 + part * 4) = vv;
                    }
                }
            }
        }
        __syncthreads();
        if (c < 7) cvt_store((c + 1) & 1);
        __syncthreads();
    }
}

// ---------------- K1 (layer 2 only): MFMA projection (R7 form) -------------
template <int L>
__global__ __launch_bounds__(512) void proj_mfma(
    const float* __restrict__ xin,
    const unsigned short* __restrict__ wt_hi,
    const unsigned short* __restrict__ wt_lo,
    const float* __restrict__ bias,
    float* __restrict__ q, unsigned short* __restrict__ kvp,
    float* __restrict__ skip, int N)
{
    constexpr int LP = L + 8;            // ushort pad
    constexpr int KS = L / 32;
    constexpr int ELEMS = 32 * (L / 4);  // float4 slots per 32-row tile
    constexpr int SI = (ELEMS + 511) / 512;
    __shared__ unsigned short xh[2][32 * LP];
    __shared__ unsigned short xl[2][32 * LP];
    __shared__ float scr[8][32 * 36];
    const int tid = threadIdx.x, lane = tid & 63, w = tid >> 6;   // w: 0..7
    const int li = lane & 15, quad = lane >> 4;
    const int slot = __builtin_amdgcn_readfirstlane(blockIdx.y * 8 + w);
    const bool hasT = slot < 13;

    int t0 = 24, t1 = 25;
    if (slot < 4)       { t0 = slot * 2; t1 = t0 + 1; }
    else if (slot < 12) { t0 = 4 + slot; t1 = 12 + slot; }   // k=8+i, v=16+i

    short8 Ah[2][KS], Al[2][KS];
    float bias_r[2][4];
    if (hasT) {
#pragma unroll
        for (int ti = 0; ti < 2; ti++) {
            int tt = ti ? t1 : t0;
#pragma unroll
            for (int ks = 0; ks < KS; ks++) {
                long off = (long)(tt * 16 + li) * L + ks * 32 + quad * 8;
                Ah[ti][ks] = *(const short8*)(wt_hi + off);
                Al[ti][ks] = *(const short8*)(wt_lo + off);
            }
#pragma unroll
            for (int r = 0; r < 4; r++)
                bias_r[ti][r] = bias[tt * 16 + quad * 4 + r];
        }
    }

    const int nb0 = blockIdx.x * 256;
    float* myscr = scr[w];
    unsigned int* su = (unsigned int*)myscr;

    float4 xv[SI];
    auto issue_loads = [&](int c) {
#pragma unroll
        for (int s = 0; s < SI; s++) {
            int f = s * 512 + tid;
            if (f < ELEMS) {
                int row = f / (L / 4), c4 = (f - row * (L / 4)) * 4;
                int n = nb0 + c * 32 + row;
                xv[s] = (n < N) ? *(const float4*)(xin + (long)n * L + c4)
                                : make_float4(0.f, 0.f, 0.f, 0.f);
            }
        }
    };
    auto cvt_store = [&](int buf) {
#pragma unroll
        for (int s = 0; s < SI; s++) {
            int f = s * 512 + tid;
            if (f < ELEMS) {
                int row = f / (L / 4), c4 = (f - row * (L / 4)) * 4;
                unsigned short h0 = f2bf(xv[s].x), h1 = f2bf(xv[s].y),
                               h2 = f2bf(xv[s].z), h3 = f2bf(xv[s].w);
                ushort4v hs = {h0, h1, h2, h3};
                ushort4v ls = {f2bf(xv[s].x - bf2f(h0)), f2bf(xv[s].y - bf2f(h1)),
                               f2bf(xv[s].z - bf2f(h2)), f2bf(xv[s].w - bf2f(h3))};
                *(ushort4v*)(xh[buf] + row * LP + c4) = hs;
                *(ushort4v*)(xl[buf] + row * LP + c4) = ls;
            }
        }
    };

    issue_loads(0);
    cvt_store(0);
    __syncthreads();

    for (int c = 0; c < 8; c++) {
        if (c < 7) issue_loads(c + 1);
        const int n0c = nb0 + c * 32;
        if (hasT) {
            const int buf = c & 1;
#pragma unroll
            for (int half = 0; half < 2; half++) {
                short8 Bh[KS], Bl[KS];
#pragma unroll
                for (int ks = 0; ks < KS; ks++) {
                    int off = (half * 16 + li) * LP + ks * 32 + quad * 8;
                    Bh[ks] = *(const short8*)(xh[buf] + off);
                    Bl[ks] = *(const short8*)(xl[buf] + off);
                }
                floatx4 accv[2];
#pragma unroll
                for (int ti = 0; ti < 2; ti++) {
                    floatx4 acc = {0.f, 0.f, 0.f, 0.f};
#pragma unroll
                    for (int ks = 0; ks < KS; ks++) {
                        acc = __builtin_amdgcn_mfma_f32_16x16x32_bf16(Ah[ti][ks], Bh[ks], acc, 0, 0, 0);
                        acc = __builtin_amdgcn_mfma_f32_16x16x32_bf16(Ah[ti][ks], Bl[ks], acc, 0, 0, 0);
                        acc = __builtin_amdgcn_mfma_f32_16x16x32_bf16(Al[ti][ks], Bh[ks], acc, 0, 0, 0);
                    }
#pragma unroll
                    for (int r = 0; r < 4; r++) acc[r] += bias_r[ti][r];
                    accv[ti] = acc;
                }
                const int row = half * 16 + li;
                if (slot < 4 || slot == 12) {
                    *(floatx4*)(myscr + row * 36 + quad * 4)      = accv[0];
                    *(floatx4*)(myscr + row * 36 + 16 + quad * 4) = accv[1];
                } else {
                    unsigned int k01 = (unsigned int)f2bf(accv[0][0]) | ((unsigned int)f2bf(accv[0][1]) << 16);
                    unsigned int k23 = (unsigned int)f2bf(accv[0][2]) | ((unsigned int)f2bf(accv[0][3]) << 16);
                    unsigned int v01 = (unsigned int)f2bf(accv[1][0]) | ((unsigned int)f2bf(accv[1][1]) << 16);
                    unsigned int v23 = (unsigned int)f2bf(accv[1][2]) | ((unsigned int)f2bf(accv[1][3]) << 16);
                    uint4 pk = make_uint4(k01, v01, k23, v23);
                    *(uint4*)(su + row * 20 + quad * 4) = pk;
                }
            }
            if (slot < 4) {
#pragma unroll
                for (int it = 0; it < 4; it++) {
                    int idx = it * 64 + lane;
                    int nl = idx >> 3, seg = idx & 7;
                    int node = n0c + nl;
                    if (node < N) {
                        floatx4 vv = *(floatx4*)(myscr + nl * 36 + seg * 4);
                        *(floatx4*)(q + (long)node * 128 + slot * 32 + seg * 4) = vv;
                    }
                }
            } else if (slot == 12) {
#pragma unroll
                for (int it = 0; it < 4; it++) {
                    int idx = it * 64 + lane;
                    int nl = idx >> 3, seg = idx & 7;
                    int node = n0c + nl;
                    if (node < N) {
                        floatx4 vv = *(floatx4*)(myscr + nl * 36 + seg * 4);
                        *(floatx4*)(skip + (long)node * 32 + seg * 4) = vv;
                    }
                }
            } else {
                const int i = slot - 4;
#pragma unroll
                for (int it = 0; it < 2; it++) {
                    int idx = it * 64 + lane;
                    int nl = idx >> 2, part = idx & 3;
                    int node = n0c + nl;
                    if (node < N) {
                        uint4 vv = *(uint4*)(su + nl * 20 + part * 4);
                        *(uint4*)((unsigned int*)(kvp + (long)node * 256) + i * 16 + part * 4) = vv;
                    }
                }
            }
        }
        __syncthreads();
        if (c < 7) cvt_store((c + 1) & 1);
        __syncthreads();
    }
}

// ---------------- K2: fused attention, 3-group rotated pipeline ------------
// FROZEN (R5 form). Five structural variants (R0/R2/R3/R4/R6) all pin the
// gather miss path at 3.2-3.45 TB/s => ~62us is this algorithm's floor.
template <bool FUSE_CLS>
__global__ __launch_bounds__(256) void attn_kernel(
    const float* __restrict__ q, const unsigned short* __restrict__ kvp,
    const int* __restrict__ rowptr, const int* __restrict__ perm,
    const float* __restrict__ skip, float* __restrict__ h,
    const float* __restrict__ wc, const float* __restrict__ bc,
    float* __restrict__ out, int N, int E)
{
    __shared__ float hrow[4][32];
    const int tid = threadIdx.x;
    const int wid = (blockIdx.x * 256 + tid) >> 6;
    const int wv = (tid >> 6) & 3;
    const int lane = tid & 63;
    if (wid >= N) return;
    const int d = __builtin_amdgcn_readfirstlane(wid);
    const int eh = lane >> 5;
    const int sl = lane & 31;
    const int hh = sl >> 3;
    const int g  = sl & 7;
    const unsigned dby = (unsigned)(hh * 64 + g * 8) * 2u;   // byte offset in 512B row
    const char* __restrict__ kvb = (const char*)kvp;
    const float4 q4 = *(const float4*)(q + (long)d * 128 + hh * 32 + g * 4);

    const int beg = rowptr[d], end = rowptr[d + 1];
    const int n = end - beg;
    const int na = (n + 1) >> 1;          // larger half (eh=0)
    const int nmin = n - na;              // smaller half (eh=1)
    const int my_off = beg + (eh ? na : 0);
    const int my_cnt = eh ? nmin : na;
    const int* __restrict__ pp = perm + my_off;   // perm has 48-entry zero pad

    float den = 0.f;
    float o0 = 0.f, o1 = 0.f, o2 = 0.f, o3 = 0.f;

    auto kvld = [&](int s) -> uint4 {
        return *(const uint4*)(kvb + ((((unsigned)s) << 9) + dby));
    };

    // ---- prime: kv for edges 0..11, perm for edges 12..23 ----
    uint4 A0, A1, A2, A3, B0, B1, B2, B3, C0, C1, C2, C3;
    int PA0, PA1, PA2, PA3, PB0, PB1, PB2, PB3, PC0, PC1, PC2, PC3;
    {
        int i0 = pp[0], i1 = pp[1], i2  = pp[2],  i3  = pp[3];
        int i4 = pp[4], i5 = pp[5], i6  = pp[6],  i7  = pp[7];
        int i8 = pp[8], i9 = pp[9], i10 = pp[10], i11 = pp[11];
        PA0 = pp[12]; PA1 = pp[13]; PA2 = pp[14]; PA3 = pp[15];
        PB0 = pp[16]; PB1 = pp[17]; PB2 = pp[18]; PB3 = pp[19];
        PC0 = pp[20]; PC1 = pp[21]; PC2 = pp[22]; PC3 = pp[23];
        A0 = kvld(i0); A1 = kvld(i1); A2 = kvld(i2);  A3 = kvld(i3);
        B0 = kvld(i4); B1 = kvld(i5); B2 = kvld(i6);  B3 = kvld(i7);
        C0 = kvld(i8); C1 = kvld(i9); C2 = kvld(i10); C3 = kvld(i11);
    }

    // group compute: 4 edge-slots (x2 halves) from G0..G3, base edge jb
    auto grp = [&](const uint4& G0, const uint4& G1, const uint4& G2,
                   const uint4& G3, int jb, auto mc) {
        constexpr bool MASKED = decltype(mc)::value;
        float p0 = q4.x * blo(G0.x) + q4.y * bhi(G0.x) + q4.z * blo(G0.z) + q4.w * bhi(G0.z);
        float p1 = q4.x * blo(G1.x) + q4.y * bhi(G1.x) + q4.z * blo(G1.z) + q4.w * bhi(G1.z);
        float p2 = q4.x * blo(G2.x) + q4.y * bhi(G2.x) + q4.z * blo(G2.z) + q4.w * bhi(G2.z);
        float p3 = q4.x * blo(G3.x) + q4.y * bhi(G3.x) + q4.z * blo(G3.z) + q4.w * bhi(G3.z);
        p0 = red8(p0); p1 = red8(p1); p2 = red8(p2); p3 = red8(p3);
        p0 = fminf(p0, 60.f); p1 = fminf(p1, 60.f);
        p2 = fminf(p2, 60.f); p3 = fminf(p3, 60.f);
        if (MASKED) {
            p0 = (jb + 0 < my_cnt) ? p0 : -INFINITY;
            p1 = (jb + 1 < my_cnt) ? p1 : -INFINITY;
            p2 = (jb + 2 < my_cnt) ? p2 : -INFINITY;
            p3 = (jb + 3 < my_cnt) ? p3 : -INFINITY;
        }
        const float w0 = EXP2F(p0), w1 = EXP2F(p1);
        const float w2 = EXP2F(p2), w3 = EXP2F(p3);
        den += (w0 + w1) + (w2 + w3);
        o0 += w0 * blo(G0.y) + w1 * blo(G1.y) + w2 * blo(G2.y) + w3 * blo(G3.y);
        o1 += w0 * bhi(G0.y) + w1 * bhi(G1.y) + w2 * bhi(G2.y) + w3 * bhi(G3.y);
        o2 += w0 * blo(G0.w) + w1 * blo(G1.w) + w2 * blo(G2.w) + w3 * blo(G3.w);
        o3 += w0 * bhi(G0.w) + w1 * bhi(G1.w) + w2 * bhi(G2.w) + w3 * bhi(G3.w);
    };

    int j = 0;
    for (; j + 12 <= nmin; j += 12) {
        grp(A0, A1, A2, A3, j, BC<false>{});
        A0 = kvld(PA0); A1 = kvld(PA1); A2 = kvld(PA2); A3 = kvld(PA3);
        PA0 = pp[j + 24]; PA1 = pp[j + 25]; PA2 = pp[j + 26]; PA3 = pp[j + 27];
        grp(B0, B1, B2, B3, j + 4, BC<false>{});
        B0 = kvld(PB0); B1 = kvld(PB1); B2 = kvld(PB2); B3 = kvld(PB3);
        PB0 = pp[j + 28]; PB1 = pp[j + 29]; PB2 = pp[j + 30]; PB3 = pp[j + 31];
        grp(C0, C1, C2, C3, j + 8, BC<false>{});
        C0 = kvld(PC0); C1 = kvld(PC1); C2 = kvld(PC2); C3 = kvld(PC3);
        PC0 = pp[j + 32]; PC1 = pp[j + 33]; PC2 = pp[j + 34]; PC3 = pp[j + 35];
    }
    // masked tail: at most 12 remaining edge-slots per half (na <= nmin+1)
    if (j < na) {
        grp(A0, A1, A2, A3, j, BC<true>{});
        if (j + 4 < na) grp(B0, B1, B2, B3, j + 4, BC<true>{});
        if (j + 8 < na) grp(C0, C1, C2, C3, j + 8, BC<true>{});
    }

    // merge the two halves (pure sums — no max bookkeeping)
    den += __shfl_xor(den, 32);
    o0 += __shfl_xor(o0, 32);
    o1 += __shfl_xor(o1, 32);
    o2 += __shfl_xor(o2, 32);
    o3 += __shfl_xor(o3, 32);

    const float inv = 1.f / (den + 1e-16f);
    o0 *= inv; o1 *= inv; o2 *= inv; o3 *= inv;
    // head mean: sum over head groups (xor 8 via DPP, then xor 16), /4
    o0 = xor8add(o0); o1 = xor8add(o1);
    o2 = xor8add(o2); o3 = xor8add(o3);
    o0 += __shfl_xor(o0, 16); o1 += __shfl_xor(o1, 16);
    o2 += __shfl_xor(o2, 16); o3 += __shfl_xor(o3, 16);

    if (lane < 8) {
        float4 sk = *(const float4*)(skip + (long)d * 32 + g * 4);
        float r0 = 0.25f * o0 + sk.x;
        float r1 = 0.25f * o1 + sk.y;
        float r2 = 0.25f * o2 + sk.z;
        float r3 = 0.25f * o3 + sk.w;
        r0 = r0 > 0.f ? r0 : 0.f;
        r1 = r1 > 0.f ? r1 : 0.f;
        r2 = r2 > 0.f ? r2 : 0.f;
        r3 = r3 > 0.f ? r3 : 0.f;
        if (FUSE_CLS) {
            *(float4*)&hrow[wv][g * 4] = make_float4(r0, r1, r2, r3);
        } else {
            *(float4*)(h + (long)d * 32 + g * 4) = make_float4(r0, r1, r2, r3);
        }
    }
    if (FUSE_CLS) {
        __builtin_amdgcn_wave_barrier();   // wave-internal LDS ordering (no HW cost)
        if (lane < 40) {
            float acc = bc[lane];
#pragma unroll
            for (int l = 0; l < 32; ++l)
                acc = fmaf(hrow[wv][l], wc[l * 40 + lane], acc);
            out[(long)d * 40 + lane] = acc;
        }
    }
}

extern "C" void kernel_launch(void* const* d_in, const int* in_sizes, int n_in,
                              void* d_out, int out_size, void* d_ws, size_t ws_size,
                              hipStream_t stream)
{
    const float* x   = (const float*)d_in[0];
    const int* ei    = (const int*)d_in[1];
    const float* wq1 = (const float*)d_in[2];  const float* bq1 = (const float*)d_in[3];
    const float* wk1 = (const float*)d_in[4];  const float* bk1 = (const float*)d_in[5];
    const float* wv1 = (const float*)d_in[6];  const float* bv1 = (const float*)d_in[7];
    const float* ws1 = (const float*)d_in[8];  const float* bs1 = (const float*)d_in[9];
    const float* wq2 = (const float*)d_in[10]; const float* bq2 = (const float*)d_in[11];
    const float* wk2 = (const float*)d_in[12]; const float* bk2 = (const float*)d_in[13];
    const float* wv2 = (const float*)d_in[14]; const float* bv2 = (const float*)d_in[15];
    const float* ws2 = (const float*)d_in[16]; const float* bs2 = (const float*)d_in[17];
    const float* wc  = (const float*)d_in[18]; const float* bc  = (const float*)d_in[19];

    const int N = in_sizes[0] / 128;   // 50000
    const int E = in_sizes[1] / 2;     // 800000
    const int* src = ei;
    const int* dst = ei + E;

    // workspace layout (bytes, 256-aligned chunks)
    char* p = (char*)d_ws;
    auto take = [&](size_t bytes) { char* r = p; p += (bytes + 255) & ~(size_t)255; return r; };
    float* q             = (float*)take((size_t)N * 128 * 4);
    unsigned short* kvp  = (unsigned short*)take((size_t)N * 256 * 2);
    float* skip          = (float*)take((size_t)N * 32 * 4);
    float* h1            = (float*)take((size_t)N * 32 * 4);
    unsigned short* wt1h = (unsigned short*)take(416 * 128 * 2);
    unsigned short* wt1l = (unsigned short*)take(416 * 128 * 2);
    unsigned short* wt2h = (unsigned short*)take(416 * 32 * 2);
    unsigned short* wt2l = (unsigned short*)take(416 * 32 * 2);
    float* bias1         = (float*)take(416 * 4);
    float* bias2         = (float*)take(416 * 4);
    int* deg             = (int*)take((size_t)N * 4);
    int* rowptr          = (int*)take((size_t)(N + 1) * 4);
    int* cursor          = (int*)take((size_t)N * 4);
    int* perm            = (int*)take((size_t)(E + 48) * 4);   // +48 zero pad
    int* bsum            = (int*)take(64 * 4);
    int* boff            = (int*)take(64 * 4);

    const int projNB   = (N + 255) / 256;               // 196
    const int eGrid256 = (E + 255) / 256;               // 3125 (hist part)
    const int eGrid512 = (E + 511) / 512;               // 1563 (fill part)
    const int attnGrid = (N + 3) / 4;                   // 4 waves/block
    const int nb       = (N + 1023) / 1024;             // <= 64

    // ---------------- prep: [memset deg] -> [wprep ∥ hist] -> scans --------
    hipMemsetAsync(deg, 0, (size_t)N * 4, stream);
    wprep_hist<<<832 + eGrid256, 256, 0, stream>>>(
        wq1, bq1, wk1, bk1, wv1, bv1, ws1, bs1,
        wq2, bq2, wk2, bk2, wv2, bv2, ws2, bs2,
        wt1h, wt1l, bias1, wt2h, wt2l, bias2,
        dst, deg, E);
    scan_part<<<nb, 256, 0, stream>>>(deg, bsum, N);
    scan_tops<<<1, 64, 0, stream>>>(bsum, boff, rowptr, nb, N, perm, E);
    scan_final<<<nb, 256, 0, stream>>>(deg, boff, rowptr, cursor, N);

    // ---------------- [proj1 ∥ fill] -> attn1 ------------------------------
    proj1_fill<<<projNB * 2 + eGrid512, 512, 0, stream>>>(
        x, wt1h, wt1l, bias1, q, kvp, skip, N, projNB,
        src, dst, cursor, perm, E);
    attn_kernel<false><<<attnGrid, 256, 0, stream>>>(q, kvp, rowptr, perm, skip, h1,
                                                     wc, bc, (float*)d_out, N, E);

    // ---------------- layer 2 (classifier fused into attn epilogue) --------
    proj_mfma<32><<<dim3(projNB, 2), 512, 0, stream>>>(h1, wt2h, wt2l, bias2,
                                                       q, kvp, skip, N);
    attn_kernel<true><<<attnGrid, 256, 0, stream>>>(q, kvp, rowptr, perm, skip, h1,
                                                    wc, bc, (float*)d_out, N, E);
}